// Round 7
// baseline (211.525 us; speedup 1.0000x reference)
//
#include <hip/hip_runtime.h>
#include <math.h>

// TopKRouter: logits = x(16384x2048) @ W(2048x64) + b; softmax E=64; top-2.
// Output: d_out[0:32768] = indices (as float), d_out[32768:65536] = probs.
//
// Round 7: occupancy push. RM=16 rows/block (grid 1024), BKC=32, LDS 17.4 KB,
// launch_bounds(256,3) -> 3 waves/SIMD. W in fragment-linear order (contiguous
// 1KB/wave frag loads, double-buffered); x LDS-staged as packed (hi|lo<<16)
// fp16 pairs, distance-2 register prefetch. Split-3 numerics (x=xh+xl*2^-11,
// W likewise, lo pre-scaled 2^11), validated epilogue.

#define D_DIM 2048
#define E_DIM 64
#define M_DIM 16384
#define RM 16             // rows per block
#define BKC 32            // k per chunk (= one MFMA k-block)
#define NCH 16            // chunks per wave (512/32)
#define XSTR 34           // padded LDS row stride in uints

typedef _Float16 half8 __attribute__((ext_vector_type(8)));
typedef float floatx4 __attribute__((ext_vector_type(4)));
typedef unsigned int uint;

// ---------------- kernel 1: W split into fragment-linear layout ----------------
// For k-step g (32 k), tile t, plane p (0=hi,1=lo):
//   wsT[((g*4+t)*2+p)*512 + (quad*16+c)*8 + j] = plane(W[g*32+quad*8+j][16t+c])
__global__ __launch_bounds__(256) void split_w_kernel(
    const float* __restrict__ Wm, _Float16* __restrict__ wsT)
{
    const int tid = threadIdx.x;
    const int n   = tid & 63;
    const int kk0 = tid >> 6;           // 0..3
    const int g   = blockIdx.x;         // 0..63
    #pragma unroll
    for (int r = 0; r < 8; r++) {
        const int kk = kk0 + r * 4;     // 0..31
        const float v = Wm[(size_t)(g * 32 + kk) * E_DIM + n];
        const _Float16 h = (_Float16)v;
        const _Float16 l = (_Float16)((v - (float)h) * 2048.0f);
        const int t = n >> 4, cc = n & 15, qd = kk >> 3, j = kk & 7;
        const size_t base = (size_t)((g * 4 + t) * 2) * 512 + (size_t)(qd * 16 + cc) * 8 + j;
        wsT[base]       = h;
        wsT[base + 512] = l;
    }
}

// ---------------- kernel 2: LDS-staged MFMA GEMM + softmax + top-2 ----------------
__global__ __launch_bounds__(256, 3) void router_mfma_kernel(
    const float* __restrict__ x, const _Float16* __restrict__ wsT,
    const float* __restrict__ bias, float* __restrict__ out)
{
    __shared__ uint xbuf[4][2][RM * XSTR];   // [wave][buf][row*XSTR + k]  (17408 B)

    const int lane = threadIdx.x & 63;
    const int wave = threadIdx.x >> 6;
    const int c    = lane & 15;
    const int quad = lane >> 4;
    const int r0   = blockIdx.x * RM;
    const int kb   = wave * (D_DIM / 4);     // 512 per wave

    // staging source: inst i covers rows i*8 + (lane>>3), k = (lane&7)*4
    const float* xg = x + (size_t)(r0 + (lane >> 3)) * D_DIM + kb + (lane & 7) * 4;
    const _Float16* wbase = wsT + (size_t)(wave * 16) * 4096 + lane * 8;

    floatx4 accm[4] = {};
    floatx4 accl[4] = {};
    float4 xa[2], xb[2];
    half8 wh0[4], wl0[4], wh1[4], wl1[4];

    auto loadx = [&](int n, float4* dst) {
        const int nn = n < NCH ? n : NCH - 1;
        #pragma unroll
        for (int i = 0; i < 2; i++)
            dst[i] = *reinterpret_cast<const float4*>(xg + (size_t)i * 8 * D_DIM + nn * BKC);
    };
    auto stage = [&](int buf, const float4* src) {
        uint* dst = &xbuf[wave][buf][0];
        #pragma unroll
        for (int i = 0; i < 2; i++) {
            const int row = i * 8 + (lane >> 3);
            const float v[4] = {src[i].x, src[i].y, src[i].z, src[i].w};
            uint p[4];
            #pragma unroll
            for (int q = 0; q < 4; q++) {
                const _Float16 h = (_Float16)v[q];
                const _Float16 l = (_Float16)((v[q] - (float)h) * 2048.0f);
                p[q] = (uint)__builtin_bit_cast(unsigned short, h)
                     | ((uint)__builtin_bit_cast(unsigned short, l) << 16);
            }
            *reinterpret_cast<uint4*>(dst + row * XSTR + (lane & 7) * 4) =
                make_uint4(p[0], p[1], p[2], p[3]);
        }
    };
    auto loadW = [&](int u, half8* wh, half8* wl) {   // u = local k-step 0..15
        const int uu = u < NCH ? u : NCH - 1;
        const _Float16* p = wbase + (size_t)uu * 4096;
        #pragma unroll
        for (int t = 0; t < 4; t++) {
            wh[t] = *reinterpret_cast<const half8*>(p + t * 1024);
            wl[t] = *reinterpret_cast<const half8*>(p + t * 1024 + 512);
        }
    };
    auto step = [&](int buf, const half8* wh, const half8* wl) {
        const uint* rp = &xbuf[wave][buf][c * XSTR + quad * 8];
        uint u8[8];
        *reinterpret_cast<uint4*>(u8)     = *reinterpret_cast<const uint4*>(rp);
        *reinterpret_cast<uint4*>(u8 + 4) = *reinterpret_cast<const uint4*>(rp + 4);
        uint hh[4], ll[4];
        #pragma unroll
        for (int q = 0; q < 4; q++) {
            hh[q] = (u8[2 * q] & 0xffffu) | (u8[2 * q + 1] << 16);
            ll[q] = (u8[2 * q] >> 16) | (u8[2 * q + 1] & 0xffff0000u);
        }
        const half8 ah = __builtin_bit_cast(half8, make_uint4(hh[0], hh[1], hh[2], hh[3]));
        const half8 al = __builtin_bit_cast(half8, make_uint4(ll[0], ll[1], ll[2], ll[3]));
        #pragma unroll
        for (int t = 0; t < 4; t++) {
            accm[t] = __builtin_amdgcn_mfma_f32_16x16x32_f16(ah, wh[t], accm[t], 0, 0, 0);
            accl[t] = __builtin_amdgcn_mfma_f32_16x16x32_f16(al, wh[t], accl[t], 0, 0, 0);
            accl[t] = __builtin_amdgcn_mfma_f32_16x16x32_f16(ah, wl[t], accl[t], 0, 0, 0);
        }
    };

    // prologue
    loadx(0, xa);
    loadx(1, xb);
    loadW(0, wh0, wl0);
    stage(0, xa);

    #pragma unroll 1
    for (int n = 0; n < NCH; n += 2) {
        loadx(n + 2, xa);
        loadW(n + 1, wh1, wl1);
        stage(1, xb);                      // chunk n+1 -> buf1
        step(0, wh0, wl0);                 // chunk n
        loadx(n + 3, xb);
        loadW(n + 2, wh0, wl0);
        if (n + 2 < NCH) stage(0, xa);     // chunk n+2 -> buf0
        step(1, wh1, wl1);                 // chunk n+1
    }

    // ---- cross-wave reduction (red aliases xbuf after barrier) ----
    __syncthreads();
    float* red = reinterpret_cast<float*>(&xbuf[0][0][0]);   // red[(w*16+row)*65 + col]
    const float scale = 1.0f / 2048.0f;
    #pragma unroll
    for (int t = 0; t < 4; t++)
        #pragma unroll
        for (int i = 0; i < 4; i++)
            red[(wave * 16 + quad * 4 + i) * 65 + c + 16 * t] =
                accm[t][i] + accl[t][i] * scale;
    __syncthreads();

    if (wave != 0) return;

    float bvt[4];
    #pragma unroll
    for (int t = 0; t < 4; t++) bvt[t] = bias[c + 16 * t];

    #pragma unroll
    for (int i = 0; i < 4; i++) {
        const int row = quad * 4 + i;
        float lt[4];
        #pragma unroll
        for (int t = 0; t < 4; t++) {
            const int col = c + 16 * t;
            lt[t] = red[(0 * 16 + row) * 65 + col] + red[(1 * 16 + row) * 65 + col]
                  + red[(2 * 16 + row) * 65 + col] + red[(3 * 16 + row) * 65 + col] + bvt[t];
        }
        const float l0 = lt[0], l1 = lt[1], l2 = lt[2], l3 = lt[3];

        float m = fmaxf(fmaxf(l0, l1), fmaxf(l2, l3));
        #pragma unroll
        for (int off = 1; off < 16; off <<= 1)
            m = fmaxf(m, __shfl_xor(m, off, 64));

        const float e0 = expf(l0 - m), e1 = expf(l1 - m);
        const float e2 = expf(l2 - m), e3 = expf(l3 - m);
        float s = e0 + e1 + e2 + e3;
        #pragma unroll
        for (int off = 1; off < 16; off <<= 1)
            s += __shfl_xor(s, off, 64);

        const float p0 = e0 / s, p1 = e1 / s, p2 = e2 / s, p3 = e3 / s;

        // keys: (prob bits << 32) | (63 - expert); experts c, c+16, c+32, c+48
        const unsigned long long ka =
            ((unsigned long long)__float_as_uint(p0) << 32) | (unsigned long long)(63 - c);
        const unsigned long long kb_ =
            ((unsigned long long)__float_as_uint(p1) << 32) | (unsigned long long)(47 - c);
        const unsigned long long kc_ =
            ((unsigned long long)__float_as_uint(p2) << 32) | (unsigned long long)(31 - c);
        const unsigned long long kd =
            ((unsigned long long)__float_as_uint(p3) << 32) | (unsigned long long)(15 - c);

        unsigned long long hi1 = ka > kb_ ? ka : kb_, lo1 = ka > kb_ ? kb_ : ka;
        unsigned long long hi2 = kc_ > kd ? kc_ : kd, lo2 = kc_ > kd ? kd : kc_;
        unsigned long long k1 = hi1 > hi2 ? hi1 : hi2;
        unsigned long long mn = hi1 > hi2 ? hi2 : hi1;
        unsigned long long mx = lo1 > lo2 ? lo1 : lo2;
        unsigned long long k2 = mn > mx ? mn : mx;

        #pragma unroll
        for (int off = 1; off < 16; off <<= 1) {
            const unsigned long long o1 = __shfl_xor(k1, off, 64);
            const unsigned long long o2 = __shfl_xor(k2, off, 64);
            const unsigned long long n1 = k1 > o1 ? k1 : o1;
            const unsigned long long w1 = k1 > o1 ? o1 : k1;   // loser of firsts
            const unsigned long long w2 = k2 > o2 ? k2 : o2;   // best of seconds
            k1 = n1;
            k2 = w1 > w2 ? w1 : w2;
        }

        if (c == 0) {
            const int gr = r0 + row;
            out[gr * 2 + 0] = (float)(63 - (int)(k1 & 0xFFFFFFFFull));
            out[gr * 2 + 1] = (float)(63 - (int)(k2 & 0xFFFFFFFFull));
            out[M_DIM * 2 + gr * 2 + 0] = __uint_as_float((unsigned)(k1 >> 32));
            out[M_DIM * 2 + gr * 2 + 1] = __uint_as_float((unsigned)(k2 >> 32));
        }
    }
}

extern "C" void kernel_launch(void* const* d_in, const int* in_sizes, int n_in,
                              void* d_out, int out_size, void* d_ws, size_t ws_size,
                              hipStream_t stream) {
    const float* x  = (const float*)d_in[0];
    const float* Wm = (const float*)d_in[1];
    const float* b  = (const float*)d_in[2];
    float* out = (float*)d_out;
    _Float16* wsT = (_Float16*)d_ws;   // 512 KB

    split_w_kernel<<<dim3(64), dim3(256), 0, stream>>>(Wm, wsT);
    router_mfma_kernel<<<dim3(M_DIM / RM), dim3(256), 0, stream>>>(x, wsT, b, out);
}